// Round 10
// baseline (92.946 us; speedup 1.0000x reference)
//
#include <hip/hip_runtime.h>

static constexpr int  D   = 64;        // embedding dim (C)
static constexpr int  KC  = 1024;      // codebook size
static constexpr int  HW  = 4096;      // 64*64
static constexpr long QSZ = 16L*64*64*64;  // elems per output tensor
static constexpr float GAPT = 0.025f;  // acc-domain gap; f16 2-term sigma ~3e-3 (R9-proven)

// ---- d_ws layout (bytes) ----
static constexpr size_t WS_ENORM = 0;        // f32[1024] +sum e^2 (recheck)
static constexpr size_t WS_ENH   = 4096;     // f32[1024] -0.5*sum e^2 (C-init)
static constexpr size_t REC      = 4096;     // per-16-col chunk record:
                                             //  [0,2048)    Eh f16 [g8][col16][8]
                                             //  [2048,4096) El f16 same layout
static constexpr size_t WS_ES    = 8192;     // 64 records = 262144 B
static constexpr size_t WS_CNT   = WS_ES + 64 * REC;    // 270336
static constexpr size_t WS_LIST  = WS_CNT + 4;
static constexpr size_t WS_NEED  = WS_LIST + 65536 * 4; // 532484 (same as R5-proven)

typedef __attribute__((ext_vector_type(8))) _Float16 f16x8;  // 8 f16 (4 VGPR)
typedef __attribute__((ext_vector_type(4))) float    f32x4;  // MFMA C/D

__device__ __forceinline__ void gload_lds16(const void* g, void* l) {
  __builtin_amdgcn_global_load_lds(
      (const __attribute__((address_space(1))) void*)g,
      (__attribute__((address_space(3))) void*)l, 16, 0, 0);
}

// ---------------------------------------------------------------------------
// prep: f16 hi/lo split of E into chunk records; enorm; enormh; cnt=0
// ---------------------------------------------------------------------------
__global__ void __launch_bounds__(64) prep_kernel(const float* __restrict__ E,
                                                  float* __restrict__ enorm,
                                                  float* __restrict__ enormh,
                                                  char* __restrict__ Es,
                                                  int* __restrict__ cnt) {
  const int k = blockIdx.x, c = threadIdx.x;
  if (k == 0 && c == 0) *cnt = 0;
  const float v = E[k * D + c];
  const _Float16 hx = (_Float16)v;
  const float    r  = v - (float)hx;   // exact
  const _Float16 lx = (_Float16)r;
  char* rec = Es + (size_t)(k >> 4) * REC;
  const int col = k & 15, g = c >> 3, j = c & 7;
  *(_Float16*)(rec +        2 * (g * 128 + col * 8 + j)) = hx;
  *(_Float16*)(rec + 2048 + 2 * (g * 128 + col * 8 + j)) = lx;
  float s = v * v;
#pragma unroll
  for (int off = 32; off; off >>= 1) s += __shfl_down(s, off, 64);
  if (c == 0) { enorm[k] = s; enormh[k] = -0.5f * s; }
}

// ---------------------------------------------------------------------------
// main kernel: 1024 blocks x 256 thr. Block = one (b,h) tile of 64 rows.
// Wave = K-QUARTER x all 64 rows (mi=4): each B-fragment ds_read feeds 4
// MFMAs. Wave-private LDS double-buffer staged via global_load_lds with
// counted s_waitcnt vmcnt(4) -- NO in-loop barriers (R9-proven mechanics).
// f16 2-term: acc = -0.5||e||^2 + fh.(eh+el); argMAX; 4-VALU top-2 tracking.
// D1 16-lane merge + D2 4-quarter LDS merge (R3-proven) + fused outputs (R7).
// ---------------------------------------------------------------------------
__global__ void __launch_bounds__(256)
vq_mfma_kernel(const float* __restrict__ X,
               const float* __restrict__ E,
               const float* __restrict__ enormh,
               const char* __restrict__ Es,
               float* __restrict__ out,
               int* __restrict__ cnt,
               int* __restrict__ list) {
  __shared__ float Xt[64][65];                       // 16.6 KB, row-major X tile
  __shared__ __attribute__((aligned(16))) char Bs[4][2][4096];  // 32.8 KB
  __shared__ float sc1[4][64], sc2[4][64];
  __shared__ int   ids[4][64], idx_s[64];

  const int tid  = threadIdx.x;
  const int wave = tid >> 6;
  const int lane = tid & 63;
  const int c15  = lane & 15;
  const int kg   = lane >> 4;
  const int bh   = blockIdx.x;
  const int b    = bh >> 6;
  const int h    = bh & 63;

  // ---- per-wave en table: 256 cols -> 4 VGPRs (coalesced) ----
  float en_reg[4];
#pragma unroll
  for (int j = 0; j < 4; ++j)
    en_reg[j] = enormh[(wave << 8) + j * 64 + lane];

  // ---- prologue: stage this wave's chunks 0,1 (4 gload_lds16 each) ----
  const char* __restrict__ EsQ = Es + (size_t)(wave * 16) * REC;
#pragma unroll
  for (int ch = 0; ch < 2; ++ch)
#pragma unroll
    for (int is = 0; is < 4; ++is)
      gload_lds16(EsQ + ch * REC + is * 1024 + lane * 16, &Bs[wave][ch][is * 1024]);

  // ---- phase A: stage 64x64 X-slice transposed (coalesced) ----
  const float* __restrict__ xbase = X + (size_t)b * (D * HW) + h * 64;
  {
    const int w = tid & 63, c0 = tid >> 6;
#pragma unroll
    for (int i = 0; i < 16; ++i)
      Xt[w][c0 + i * 4] = xbase[(c0 + i * 4) * HW + w];
  }
  __syncthreads();   // Xt + chunks 0,1 all drained; vmcnt clean for counting

  // ---- phase B: A-fragments (f16 hi only) for ALL 64 rows ----
  f16x8 ah[4][2];
#pragma unroll
  for (int mi = 0; mi < 4; ++mi)
#pragma unroll
    for (int ks = 0; ks < 2; ++ks) {
      const float* xp = &Xt[mi * 16 + c15][ks * 32 + kg * 8];
      f16x8 v;
#pragma unroll
      for (int j = 0; j < 8; ++j) v[j] = (_Float16)xp[j];
      ah[mi][ks] = v;
    }

  // ---- phase C: 16 chunks of 16 cols, wave-private dbuf, counted vmcnt ----
  float b1[4][4], b2[4][4]; int i1[4][4];
#pragma unroll
  for (int mi = 0; mi < 4; ++mi)
#pragma unroll
    for (int r = 0; r < 4; ++r) { b1[mi][r] = -3.4e38f; b2[mi][r] = -3.4e38f; i1[mi][r] = 0; }

  const int eo = 2 * (kg * 128 + c15 * 8);
#pragma unroll
  for (int t = 0; t < 16; ++t) {
    if (t < 15) asm volatile("s_waitcnt vmcnt(4)" ::: "memory");  // chunk t landed
    else        asm volatile("s_waitcnt vmcnt(0)" ::: "memory");
    __builtin_amdgcn_sched_barrier(0);
    const char* bp = &Bs[wave][t & 1][0];
    const f16x8 h0 = *(const f16x8*)(bp + eo);
    const f16x8 h1 = *(const f16x8*)(bp + eo + 1024);
    const f16x8 l0 = *(const f16x8*)(bp + 2048 + eo);
    const f16x8 l1 = *(const f16x8*)(bp + 2048 + eo + 1024);
    const float en = __shfl(en_reg[t >> 2], ((t & 3) << 4) + c15, 64);  // static idx
    const int   col = (wave << 8) + (t << 4) + c15;
#pragma unroll
    for (int mi = 0; mi < 4; ++mi) {
      f32x4 acc = {en, en, en, en};
      acc = __builtin_amdgcn_mfma_f32_16x16x32_f16(ah[mi][0], h0, acc, 0, 0, 0);
      acc = __builtin_amdgcn_mfma_f32_16x16x32_f16(ah[mi][1], h1, acc, 0, 0, 0);
      acc = __builtin_amdgcn_mfma_f32_16x16x32_f16(ah[mi][0], l0, acc, 0, 0, 0);
      acc = __builtin_amdgcn_mfma_f32_16x16x32_f16(ah[mi][1], l1, acc, 0, 0, 0);
#pragma unroll
      for (int r = 0; r < 4; ++r) {
        const float x  = acc[r];
        const bool  gt = x > b1[mi][r];
        b2[mi][r] = __builtin_amdgcn_fmed3f(b2[mi][r], x, b1[mi][r]);  // 2nd-best
        b1[mi][r] = gt ? x   : b1[mi][r];
        i1[mi][r] = gt ? col : i1[mi][r];
      }
    }
    __builtin_amdgcn_sched_barrier(0);
    if (t < 14) {   // stage chunk t+2 into the buffer just consumed
#pragma unroll
      for (int is = 0; is < 4; ++is)
        gload_lds16(EsQ + (size_t)(t + 2) * REC + is * 1024 + lane * 16,
                    &Bs[wave][t & 1][is * 1024]);
    }
  }

  // ---- phase D1: merge top-2 across the 16 col-lanes (MAX semantics) ----
#pragma unroll
  for (int mi = 0; mi < 4; ++mi) {
#pragma unroll
    for (int r = 0; r < 4; ++r) {
      float B1 = b1[mi][r], B2 = b2[mi][r]; int I1 = i1[mi][r];
#pragma unroll
      for (int m = 1; m < 16; m <<= 1) {
        const float o1 = __shfl_xor(B1, m, 64);
        const float o2 = __shfl_xor(B2, m, 64);
        const int   oi = __shfl_xor(I1, m, 64);
        const float n2 = fmaxf(fmaxf(B2, o2), fminf(B1, o1));
        if (o1 > B1) { B1 = o1; I1 = oi; }
        B2 = n2;
      }
      if (c15 == 0) {
        const int rl = mi * 16 + kg * 4 + r;     // row in 64-tile
        sc1[wave][rl] = B1; sc2[wave][rl] = B2; ids[wave][rl] = I1;
      }
    }
  }
  __syncthreads();

  // ---- phase D2: merge the 4 quarters (ascending col order); flag ties ----
  if (tid < 64) {
    float g1 = sc1[0][tid], g2 = sc2[0][tid]; int gi = ids[0][tid];
#pragma unroll
    for (int wv = 1; wv < 4; ++wv) {
      const float s1 = sc1[wv][tid], s2 = sc2[wv][tid];
      const int   ii = ids[wv][tid];
      if (s1 > g1) { g2 = fmaxf(g1, s2); g1 = s1; gi = ii; }
      else         { g2 = fmaxf(g2, s1); }
    }
    idx_s[tid] = gi;
    if (g1 - g2 < GAPT) {                  // near-tie -> exact recheck
      const int pos = atomicAdd(cnt, 1);
      if (pos < 65536) list[pos] = bh * 64 + tid;
    }
  }
  __syncthreads();

  // ---- phase E: fused outputs (coalesced; gather overlaid onto Xt) ----
  float* __restrict__ lat = out + QSZ;
  float* __restrict__ ql  = out + 2 * QSZ;
  const size_t n0 = (size_t)bh * 64;

#pragma unroll
  for (int i = 0; i < 16; ++i) {
    const int e_ = i * 256 + tid;
    const int w = e_ >> 6, c = e_ & 63;
    const float q = E[idx_s[w] * D + c];    // coalesced gather (w uniform/group)
    ql[(n0 + w) * D + c]  = q;
    lat[(n0 + w) * D + c] = Xt[w][c];
    Xt[w][c] = q;                            // overlay for quantized pass
  }
  __syncthreads();
  float* __restrict__ qb = out + (size_t)b * (D * HW) + h * 64;
#pragma unroll
  for (int i = 0; i < 16; ++i) {
    const int e_ = i * 256 + tid;
    const int c = e_ >> 6, w = e_ & 63;
    qb[c * HW + w] = Xt[w][c];
  }
}

// ---------------------------------------------------------------------------
// exact fp32 recheck for flagged rows (lowest-index tie-break), 1 wave/row
// ---------------------------------------------------------------------------
__global__ void __launch_bounds__(64) recheck_kernel(const float* __restrict__ X,
                                                     const float* __restrict__ E,
                                                     const float* __restrict__ enorm,
                                                     const int* __restrict__ cnt,
                                                     const int* __restrict__ list,
                                                     float* __restrict__ out) {
  __shared__ float fsh[64];
  const int lane = threadIdx.x;
  const int n = min(*cnt, 65536);
  for (int ii = blockIdx.x; ii < n; ii += gridDim.x) {
    const int row = list[ii];
    const int b = row >> 12, h = (row >> 6) & 63, w = row & 63;
    fsh[lane] = X[((size_t)b * D + lane) * HW + h * 64 + w];
    __syncthreads();
    float best = 3.4e38f; int bidx = 0;
    for (int j = 0; j < 16; ++j) {
      const int k = lane + j * 64;
      const float* __restrict__ e = E + k * D;
      float a0 = 0.f, a1 = 0.f, a2 = 0.f, a3 = 0.f;
#pragma unroll
      for (int c = 0; c < D; c += 4) {
        a0 = fmaf(fsh[c + 0], e[c + 0], a0);
        a1 = fmaf(fsh[c + 1], e[c + 1], a1);
        a2 = fmaf(fsh[c + 2], e[c + 2], a2);
        a3 = fmaf(fsh[c + 3], e[c + 3], a3);
      }
      const float s = enorm[k] - 2.0f * ((a0 + a1) + (a2 + a3));
      if (s < best) { best = s; bidx = k; }
    }
#pragma unroll
    for (int m = 1; m < 64; m <<= 1) {
      const float ob = __shfl_xor(best, m, 64);
      const int   oi = __shfl_xor(bidx, m, 64);
      if (ob < best || (ob == best && oi < bidx)) { best = ob; bidx = oi; }
    }
    const float q = E[bidx * D + lane];
    float* __restrict__ ql = out + 2 * QSZ;
    ql[(size_t)row * D + lane] = q;
    out[((size_t)b * D + lane) * HW + h * 64 + w] = q;
    __syncthreads();
  }
}

// ---------------------------------------------------------------------------
// fallback (R1 kernels) if ws_size is too small for the staged tables
// ---------------------------------------------------------------------------
__global__ void __launch_bounds__(64) enorm_kernel(const float* __restrict__ E,
                                                   float* __restrict__ enorm) {
  const int k = blockIdx.x, c = threadIdx.x;
  float v = E[k * D + c];
  float s = v * v;
#pragma unroll
  for (int off = 32; off; off >>= 1) s += __shfl_down(s, off, 64);
  if (c == 0) enorm[k] = s;
}

__global__ void __launch_bounds__(256) vq_kernel(const float* __restrict__ X,
                                                 const float* __restrict__ E,
                                                 const float* __restrict__ enorm,
                                                 float* __restrict__ out) {
  const int bh = blockIdx.x, b = bh >> 6, h = bh & 63;
  const int tid = threadIdx.x, wave = tid >> 6, lane = tid & 63;
  const float* __restrict__ xbase = X + (size_t)b * (D * HW) + h * 64;
  float f[D];
#pragma unroll
  for (int c = 0; c < D; ++c) f[c] = xbase[c * HW + lane];
  float best = 3.4e38f; int bidx = 0;
  const int k0 = wave * (KC / 4);
  for (int k = k0; k < k0 + (KC / 4); ++k) {
    const float* __restrict__ e = E + k * D;
    float a0 = 0.f, a1 = 0.f, a2 = 0.f, a3 = 0.f;
#pragma unroll
    for (int c = 0; c < D; c += 4) {
      a0 = fmaf(f[c + 0], e[c + 0], a0);
      a1 = fmaf(f[c + 1], e[c + 1], a1);
      a2 = fmaf(f[c + 2], e[c + 2], a2);
      a3 = fmaf(f[c + 3], e[c + 3], a3);
    }
    const float score = enorm[k] - 2.0f * ((a0 + a1) + (a2 + a3));
    if (score < best) { best = score; bidx = k; }
  }
  __shared__ float sc_s[4][64]; __shared__ int id_s[4][64];
  __shared__ int idx_s[64]; __shared__ float tile[64 * 65]; __shared__ float eq[64 * 65];
  sc_s[wave][lane] = best; id_s[wave][lane] = bidx;
  if (wave == 0) {
#pragma unroll
    for (int c = 0; c < D; ++c) tile[c * 65 + lane] = f[c];
  }
  __syncthreads();
  if (tid < 64) {
    float bs = sc_s[0][tid]; int bi = id_s[0][tid];
#pragma unroll
    for (int wv = 1; wv < 4; ++wv) {
      if (sc_s[wv][tid] < bs) { bs = sc_s[wv][tid]; bi = id_s[wv][tid]; }
    }
    idx_s[tid] = bi;
  }
  __syncthreads();
  float* __restrict__ qout = out;
  float* __restrict__ lat = out + QSZ;
  float* __restrict__ ql = out + 2 * QSZ;
  const size_t n0 = (size_t)bh * 64;
#pragma unroll
  for (int i = 0; i < 16; ++i) {
    const int e_ = i * 256 + tid, w = e_ >> 6, c = e_ & 63;
    const float q = E[idx_s[w] * D + c];
    eq[w * 65 + c] = q;
    ql[(n0 + w) * D + c] = q;
    lat[(n0 + w) * D + c] = tile[c * 65 + w];
  }
  __syncthreads();
  float* __restrict__ qb = qout + (size_t)b * (D * HW) + h * 64;
#pragma unroll
  for (int i = 0; i < 16; ++i) {
    const int e_ = i * 256 + tid, c = e_ >> 6, w = e_ & 63;
    qb[c * HW + w] = eq[w * 65 + c];
  }
}

extern "C" void kernel_launch(void* const* d_in, const int* in_sizes, int n_in,
                              void* d_out, int out_size, void* d_ws, size_t ws_size,
                              hipStream_t stream) {
  const float* X = (const float*)d_in[0];
  const float* E = (const float*)d_in[1];
  float* out = (float*)d_out;
  char* ws = (char*)d_ws;

  if (ws_size >= WS_NEED) {
    float* enorm  = (float*)(ws + WS_ENORM);
    float* enormh = (float*)(ws + WS_ENH);
    char*  Es     = ws + WS_ES;
    int* cnt  = (int*)(ws + WS_CNT);
    int* list = (int*)(ws + WS_LIST);
    prep_kernel<<<KC, 64, 0, stream>>>(E, enorm, enormh, Es, cnt);
    vq_mfma_kernel<<<1024, 256, 0, stream>>>(X, E, enormh, Es, out, cnt, list);
    recheck_kernel<<<1024, 64, 0, stream>>>(X, E, enorm, cnt, list, out);
  } else {
    float* enorm = (float*)ws;
    enorm_kernel<<<KC, 64, 0, stream>>>(E, enorm);
    vq_kernel<<<1024, 256, 0, stream>>>(X, E, enorm, out);
  }
}

// Round 11
// 77.699 us; speedup vs baseline: 1.1962x; 1.1962x over previous
//
#include <hip/hip_runtime.h>

static constexpr int  D   = 64;        // embedding dim (C)
static constexpr int  KC  = 1024;      // codebook size
static constexpr int  HW  = 4096;      // 64*64
static constexpr long QSZ = 16L*64*64*64;  // elems per output tensor
static constexpr float GAPT = 0.025f;  // acc-domain gap; f16 2-term sigma ~3e-3 (R9-proven)

// ---- d_ws layout (bytes) ----
static constexpr size_t WS_ENORM = 0;        // f32[1024] +sum e^2 (recheck)
static constexpr size_t REC      = 4160;     // per-16-col chunk record:
                                             //  [0,2048)    Eh f16 [g8][col16][8]
                                             //  [2048,4096) El f16 same layout
                                             //  [4096,4160) en f32[16] = -0.5*||e||^2
static constexpr size_t WS_ES    = 4096;     // 64 records = 266240 B
static constexpr size_t WS_CNT   = WS_ES + 64 * REC;    // 270336
static constexpr size_t WS_LIST  = WS_CNT + 4;
static constexpr size_t WS_NEED  = WS_LIST + 65536 * 4; // 532484 (proven available)

typedef __attribute__((ext_vector_type(8))) _Float16 f16x8;  // 8 f16 (4 VGPR)
typedef __attribute__((ext_vector_type(4))) float    f32x4;  // MFMA C/D

__device__ __forceinline__ void gload_lds16(const void* g, void* l) {
  __builtin_amdgcn_global_load_lds(
      (const __attribute__((address_space(1))) void*)g,
      (__attribute__((address_space(3))) void*)l, 16, 0, 0);
}
__device__ __forceinline__ void gload_lds4(const void* g, void* l) {
  __builtin_amdgcn_global_load_lds(
      (const __attribute__((address_space(1))) void*)g,
      (__attribute__((address_space(3))) void*)l, 4, 0, 0);
}

// ---------------------------------------------------------------------------
// prep: f16 hi/lo split of E + en tail into chunk records; enorm; cnt=0
// ---------------------------------------------------------------------------
__global__ void __launch_bounds__(64) prep_kernel(const float* __restrict__ E,
                                                  float* __restrict__ enorm,
                                                  char* __restrict__ Es,
                                                  int* __restrict__ cnt) {
  const int k = blockIdx.x, c = threadIdx.x;
  if (k == 0 && c == 0) *cnt = 0;
  const float v = E[k * D + c];
  const _Float16 hx = (_Float16)v;
  const float    r  = v - (float)hx;   // exact
  const _Float16 lx = (_Float16)r;
  char* rec = Es + (size_t)(k >> 4) * REC;
  const int col = k & 15, g = c >> 3, j = c & 7;
  *(_Float16*)(rec +        2 * (g * 128 + col * 8 + j)) = hx;
  *(_Float16*)(rec + 2048 + 2 * (g * 128 + col * 8 + j)) = lx;
  float s = v * v;
#pragma unroll
  for (int off = 32; off; off >>= 1) s += __shfl_down(s, off, 64);
  if (c == 0) { enorm[k] = s; *(float*)(rec + 4096 + col * 4) = -0.5f * s; }
}

// ---------------------------------------------------------------------------
// main kernel: 1024 blocks x 256 thr. Block = one (b,h) tile of 64 rows.
// Wave = K-QUARTER x all 64 rows (mi=4): each B-fragment ds_read feeds 4
// MFMAs. Wave-private LDS double-buffer staged via global_load_lds with
// counted s_waitcnt vmcnt(5) -- NO in-loop barriers. f16 2-term split:
// acc = -0.5||e||^2 + fh.(eh+el); argMAX; 4-VALU top-2 tracking.
// R10 fixes: unroll 2 (not full -- VGPR 172 was the regression), en values
// staged in-record (R9-proven 5-load schedule) instead of en_reg+shfl.
// ---------------------------------------------------------------------------
__global__ void __launch_bounds__(256)
vq_mfma_kernel(const float* __restrict__ X,
               const float* __restrict__ E,
               const char* __restrict__ Es,
               float* __restrict__ out,
               int* __restrict__ cnt,
               int* __restrict__ list) {
  __shared__ float Xt[64][65];                                  // 16640 B
  __shared__ __attribute__((aligned(16))) char Bs[4][2][4160];  // 33280 B
  __shared__ float sc1[4][64], sc2[4][64];                      //  2048 B
  __shared__ int   ids[4][64], idx_s[64];                       //  1280 B
                                                                // total 53248 -> 3 blk/CU
  const int tid  = threadIdx.x;
  const int wave = tid >> 6;
  const int lane = tid & 63;
  const int c15  = lane & 15;
  const int kg   = lane >> 4;
  const int bh   = blockIdx.x;
  const int b    = bh >> 6;
  const int h    = bh & 63;

  // ---- prologue: stage this wave's chunks 0,1 (5 loads each) ----
  const char* __restrict__ EsQ = Es + (size_t)(wave * 16) * REC;
#pragma unroll
  for (int ch = 0; ch < 2; ++ch) {
#pragma unroll
    for (int is = 0; is < 4; ++is)
      gload_lds16(EsQ + ch * REC + is * 1024 + lane * 16, &Bs[wave][ch][is * 1024]);
    if (lane < 16)
      gload_lds4(EsQ + ch * REC + 4096 + lane * 4, &Bs[wave][ch][4096]);
  }

  // ---- phase A: stage 64x64 X-slice transposed (coalesced) ----
  const float* __restrict__ xbase = X + (size_t)b * (D * HW) + h * 64;
  {
    const int w = tid & 63, c0 = tid >> 6;
#pragma unroll
    for (int i = 0; i < 16; ++i)
      Xt[w][c0 + i * 4] = xbase[(c0 + i * 4) * HW + w];
  }
  asm volatile("s_waitcnt vmcnt(0)" ::: "memory");
  __syncthreads();   // Xt + chunks 0,1 in LDS; vmcnt == 0 for exact counting

  // ---- phase B: A-fragments (f16 hi only) for ALL 64 rows ----
  f16x8 ah[4][2];
#pragma unroll
  for (int mi = 0; mi < 4; ++mi)
#pragma unroll
    for (int ks = 0; ks < 2; ++ks) {
      const float* xp = &Xt[mi * 16 + c15][ks * 32 + kg * 8];
      f16x8 v;
#pragma unroll
      for (int j = 0; j < 8; ++j) v[j] = (_Float16)xp[j];
      ah[mi][ks] = v;
    }

  // ---- phase C: 16 chunks of 16 cols, wave-private dbuf, counted vmcnt ----
  float b1[4][4], b2[4][4]; int i1[4][4];
#pragma unroll
  for (int mi = 0; mi < 4; ++mi)
#pragma unroll
    for (int r = 0; r < 4; ++r) { b1[mi][r] = -3.4e38f; b2[mi][r] = -3.4e38f; i1[mi][r] = 0; }

  const int eo = 2 * (kg * 128 + c15 * 8);
#pragma unroll 2
  for (int t = 0; t < 16; ++t) {
    if (t < 15) asm volatile("s_waitcnt vmcnt(5)" ::: "memory");  // chunk t landed
    else        asm volatile("s_waitcnt vmcnt(0)" ::: "memory");
    __builtin_amdgcn_sched_barrier(0);
    const char* bp = &Bs[wave][t & 1][0];
    const f16x8 h0 = *(const f16x8*)(bp + eo);
    const f16x8 h1 = *(const f16x8*)(bp + eo + 1024);
    const f16x8 l0 = *(const f16x8*)(bp + 2048 + eo);
    const f16x8 l1 = *(const f16x8*)(bp + 2048 + eo + 1024);
    const float en = *(const float*)(bp + 4096 + c15 * 4);   // 16 banks, 4-way bcast
    const int   col = (wave << 8) + (t << 4) + c15;
#pragma unroll
    for (int mi = 0; mi < 4; ++mi) {
      f32x4 acc = {en, en, en, en};
      acc = __builtin_amdgcn_mfma_f32_16x16x32_f16(ah[mi][0], h0, acc, 0, 0, 0);
      acc = __builtin_amdgcn_mfma_f32_16x16x32_f16(ah[mi][1], h1, acc, 0, 0, 0);
      acc = __builtin_amdgcn_mfma_f32_16x16x32_f16(ah[mi][0], l0, acc, 0, 0, 0);
      acc = __builtin_amdgcn_mfma_f32_16x16x32_f16(ah[mi][1], l1, acc, 0, 0, 0);
#pragma unroll
      for (int r = 0; r < 4; ++r) {
        const float x  = acc[r];
        const bool  gt = x > b1[mi][r];
        b2[mi][r] = __builtin_amdgcn_fmed3f(b2[mi][r], x, b1[mi][r]);  // 2nd-best
        b1[mi][r] = gt ? x   : b1[mi][r];
        i1[mi][r] = gt ? col : i1[mi][r];
      }
    }
    __builtin_amdgcn_sched_barrier(0);
    if (t < 14) {   // stage chunk t+2 into the buffer just consumed
#pragma unroll
      for (int is = 0; is < 4; ++is)
        gload_lds16(EsQ + (size_t)(t + 2) * REC + is * 1024 + lane * 16,
                    &Bs[wave][t & 1][is * 1024]);
      if (lane < 16)
        gload_lds4(EsQ + (size_t)(t + 2) * REC + 4096 + lane * 4,
                   &Bs[wave][t & 1][4096]);
    }
  }

  // ---- phase D1: merge top-2 across the 16 col-lanes (MAX semantics) ----
#pragma unroll
  for (int mi = 0; mi < 4; ++mi) {
#pragma unroll
    for (int r = 0; r < 4; ++r) {
      float B1 = b1[mi][r], B2 = b2[mi][r]; int I1 = i1[mi][r];
#pragma unroll
      for (int m = 1; m < 16; m <<= 1) {
        const float o1 = __shfl_xor(B1, m, 64);
        const float o2 = __shfl_xor(B2, m, 64);
        const int   oi = __shfl_xor(I1, m, 64);
        const float n2 = fmaxf(fmaxf(B2, o2), fminf(B1, o1));
        if (o1 > B1) { B1 = o1; I1 = oi; }
        B2 = n2;
      }
      if (c15 == 0) {
        const int rl = mi * 16 + kg * 4 + r;     // row in 64-tile
        sc1[wave][rl] = B1; sc2[wave][rl] = B2; ids[wave][rl] = I1;
      }
    }
  }
  __syncthreads();

  // ---- phase D2: merge the 4 quarters (ascending col order); flag ties ----
  if (tid < 64) {
    float g1 = sc1[0][tid], g2 = sc2[0][tid]; int gi = ids[0][tid];
#pragma unroll
    for (int wv = 1; wv < 4; ++wv) {
      const float s1 = sc1[wv][tid], s2 = sc2[wv][tid];
      const int   ii = ids[wv][tid];
      if (s1 > g1) { g2 = fmaxf(g1, s2); g1 = s1; gi = ii; }
      else         { g2 = fmaxf(g2, s1); }
    }
    idx_s[tid] = gi;
    if (g1 - g2 < GAPT) {                  // near-tie -> exact recheck
      const int pos = atomicAdd(cnt, 1);
      if (pos < 65536) list[pos] = bh * 64 + tid;
    }
  }
  __syncthreads();

  // ---- phase E: fused outputs (coalesced; gather overlaid onto Xt) ----
  float* __restrict__ lat = out + QSZ;
  float* __restrict__ ql  = out + 2 * QSZ;
  const size_t n0 = (size_t)bh * 64;

#pragma unroll
  for (int i = 0; i < 16; ++i) {
    const int e_ = i * 256 + tid;
    const int w = e_ >> 6, c = e_ & 63;
    const float q = E[idx_s[w] * D + c];    // coalesced gather (w uniform/group)
    ql[(n0 + w) * D + c]  = q;
    lat[(n0 + w) * D + c] = Xt[w][c];
    Xt[w][c] = q;                            // overlay for quantized pass
  }
  __syncthreads();
  float* __restrict__ qb = out + (size_t)b * (D * HW) + h * 64;
#pragma unroll
  for (int i = 0; i < 16; ++i) {
    const int e_ = i * 256 + tid;
    const int c = e_ >> 6, w = e_ & 63;
    qb[c * HW + w] = Xt[w][c];
  }
}

// ---------------------------------------------------------------------------
// exact fp32 recheck for flagged rows (lowest-index tie-break), 1 wave/row
// ---------------------------------------------------------------------------
__global__ void __launch_bounds__(64) recheck_kernel(const float* __restrict__ X,
                                                     const float* __restrict__ E,
                                                     const float* __restrict__ enorm,
                                                     const int* __restrict__ cnt,
                                                     const int* __restrict__ list,
                                                     float* __restrict__ out) {
  __shared__ float fsh[64];
  const int lane = threadIdx.x;
  const int n = min(*cnt, 65536);
  for (int ii = blockIdx.x; ii < n; ii += gridDim.x) {
    const int row = list[ii];
    const int b = row >> 12, h = (row >> 6) & 63, w = row & 63;
    fsh[lane] = X[((size_t)b * D + lane) * HW + h * 64 + w];
    __syncthreads();
    float best = 3.4e38f; int bidx = 0;
    for (int j = 0; j < 16; ++j) {
      const int k = lane + j * 64;
      const float* __restrict__ e = E + k * D;
      float a0 = 0.f, a1 = 0.f, a2 = 0.f, a3 = 0.f;
#pragma unroll
      for (int c = 0; c < D; c += 4) {
        a0 = fmaf(fsh[c + 0], e[c + 0], a0);
        a1 = fmaf(fsh[c + 1], e[c + 1], a1);
        a2 = fmaf(fsh[c + 2], e[c + 2], a2);
        a3 = fmaf(fsh[c + 3], e[c + 3], a3);
      }
      const float s = enorm[k] - 2.0f * ((a0 + a1) + (a2 + a3));
      if (s < best) { best = s; bidx = k; }
    }
#pragma unroll
    for (int m = 1; m < 64; m <<= 1) {
      const float ob = __shfl_xor(best, m, 64);
      const int   oi = __shfl_xor(bidx, m, 64);
      if (ob < best || (ob == best && oi < bidx)) { best = ob; bidx = oi; }
    }
    const float q = E[bidx * D + lane];
    float* __restrict__ ql = out + 2 * QSZ;
    ql[(size_t)row * D + lane] = q;
    out[((size_t)b * D + lane) * HW + h * 64 + w] = q;
    __syncthreads();
  }
}

// ---------------------------------------------------------------------------
// fallback (R1 kernels) if ws_size is too small for the staged tables
// ---------------------------------------------------------------------------
__global__ void __launch_bounds__(64) enorm_kernel(const float* __restrict__ E,
                                                   float* __restrict__ enorm) {
  const int k = blockIdx.x, c = threadIdx.x;
  float v = E[k * D + c];
  float s = v * v;
#pragma unroll
  for (int off = 32; off; off >>= 1) s += __shfl_down(s, off, 64);
  if (c == 0) enorm[k] = s;
}

__global__ void __launch_bounds__(256) vq_kernel(const float* __restrict__ X,
                                                 const float* __restrict__ E,
                                                 const float* __restrict__ enorm,
                                                 float* __restrict__ out) {
  const int bh = blockIdx.x, b = bh >> 6, h = bh & 63;
  const int tid = threadIdx.x, wave = tid >> 6, lane = tid & 63;
  const float* __restrict__ xbase = X + (size_t)b * (D * HW) + h * 64;
  float f[D];
#pragma unroll
  for (int c = 0; c < D; ++c) f[c] = xbase[c * HW + lane];
  float best = 3.4e38f; int bidx = 0;
  const int k0 = wave * (KC / 4);
  for (int k = k0; k < k0 + (KC / 4); ++k) {
    const float* __restrict__ e = E + k * D;
    float a0 = 0.f, a1 = 0.f, a2 = 0.f, a3 = 0.f;
#pragma unroll
    for (int c = 0; c < D; c += 4) {
      a0 = fmaf(f[c + 0], e[c + 0], a0);
      a1 = fmaf(f[c + 1], e[c + 1], a1);
      a2 = fmaf(f[c + 2], e[c + 2], a2);
      a3 = fmaf(f[c + 3], e[c + 3], a3);
    }
    const float score = enorm[k] - 2.0f * ((a0 + a1) + (a2 + a3));
    if (score < best) { best = score; bidx = k; }
  }
  __shared__ float sc_s[4][64]; __shared__ int id_s[4][64];
  __shared__ int idx_s[64]; __shared__ float tile[64 * 65]; __shared__ float eq[64 * 65];
  sc_s[wave][lane] = best; id_s[wave][lane] = bidx;
  if (wave == 0) {
#pragma unroll
    for (int c = 0; c < D; ++c) tile[c * 65 + lane] = f[c];
  }
  __syncthreads();
  if (tid < 64) {
    float bs = sc_s[0][tid]; int bi = id_s[0][tid];
#pragma unroll
    for (int wv = 1; wv < 4; ++wv) {
      if (sc_s[wv][tid] < bs) { bs = sc_s[wv][tid]; bi = id_s[wv][tid]; }
    }
    idx_s[tid] = bi;
  }
  __syncthreads();
  float* __restrict__ qout = out;
  float* __restrict__ lat = out + QSZ;
  float* __restrict__ ql = out + 2 * QSZ;
  const size_t n0 = (size_t)bh * 64;
#pragma unroll
  for (int i = 0; i < 16; ++i) {
    const int e_ = i * 256 + tid, w = e_ >> 6, c = e_ & 63;
    const float q = E[idx_s[w] * D + c];
    eq[w * 65 + c] = q;
    ql[(n0 + w) * D + c] = q;
    lat[(n0 + w) * D + c] = tile[c * 65 + w];
  }
  __syncthreads();
  float* __restrict__ qb = qout + (size_t)b * (D * HW) + h * 64;
#pragma unroll
  for (int i = 0; i < 16; ++i) {
    const int e_ = i * 256 + tid, c = e_ >> 6, w = e_ & 63;
    qb[c * HW + w] = eq[w * 65 + c];
  }
}

extern "C" void kernel_launch(void* const* d_in, const int* in_sizes, int n_in,
                              void* d_out, int out_size, void* d_ws, size_t ws_size,
                              hipStream_t stream) {
  const float* X = (const float*)d_in[0];
  const float* E = (const float*)d_in[1];
  float* out = (float*)d_out;
  char* ws = (char*)d_ws;

  if (ws_size >= WS_NEED) {
    float* enorm = (float*)(ws + WS_ENORM);
    char*  Es    = ws + WS_ES;
    int* cnt  = (int*)(ws + WS_CNT);
    int* list = (int*)(ws + WS_LIST);
    prep_kernel<<<KC, 64, 0, stream>>>(E, enorm, Es, cnt);
    vq_mfma_kernel<<<1024, 256, 0, stream>>>(X, E, Es, out, cnt, list);
    recheck_kernel<<<1024, 64, 0, stream>>>(X, E, enorm, cnt, list, out);
  } else {
    float* enorm = (float*)ws;
    enorm_kernel<<<KC, 64, 0, stream>>>(E, enorm);
    vq_kernel<<<1024, 256, 0, stream>>>(X, E, enorm, out);
  }
}